// Round 2
// baseline (259.683 us; speedup 1.0000x reference)
//
#include <hip/hip_runtime.h>

// Conv 3x3 VALID, NCHW/OIHW, fp32. x=[64,3,224,224], w=[16,3,3,3] -> out=[64,16,222,222].
// Memory-bound (202 MB output write). Each thread: 4 consecutive ow x all 16 oc.

namespace {
constexpr int B  = 64, C = 3, H = 224, W = 224;
constexpr int OC = 16, KS = 3, OH = 222, OW = 222;
constexpr int NW4   = 56;               // ceil(OW/4)
constexpr int TOTAL = B * OH * NW4;     // 795,648 (= 3108 * 256 exactly)
constexpr int BLOCK = 256;
}

__global__ __launch_bounds__(BLOCK) void conv3x3_kernel(
    const float* __restrict__ x, const float* __restrict__ flt,
    float* __restrict__ out) {
  // Stage filters in LDS, padded [16][28] so each oc row is 112 B (7 x 16 B)
  // -> per-oc reload is 7 aligned ds_read_b128 broadcasts.
  __shared__ float flds[OC * 28];
  const int lt = threadIdx.x;
  for (int e = lt; e < OC * 27; e += BLOCK) {
    const int oc = e / 27;
    const int r  = e - oc * 27;
    flds[oc * 28 + r] = flt[e];
  }
  __syncthreads();

  const int tid = blockIdx.x * BLOCK + lt;
  if (tid >= TOTAL) return;
  const int g  = tid % NW4;
  const int t1 = tid / NW4;
  const int oh = t1 % OH;
  const int b  = t1 / OH;
  const int w0 = g * 4;
  const bool tail = (w0 + 4 > OW);        // only g == 55 (w0 = 220)
  const int  wb   = tail ? w0 : w0 + 4;   // clamped second-load column (avoids OOB)

  // Load the 3x3x6 input window as 2 aligned float4 per (c,row) = 18 vec loads.
  // For the tail group, c8[..][4..7] duplicates cols 220..223; those values only
  // feed output columns >= 222, which are masked at the store.
  float c8[C][KS][8];
  const float* xb = x + (size_t)b * (C * H * W);
#pragma unroll
  for (int c = 0; c < C; ++c) {
#pragma unroll
    for (int r = 0; r < KS; ++r) {
      const float* row = xb + (c * H + oh + r) * W;
      const float4 a  = *reinterpret_cast<const float4*>(row + w0);
      const float4 bb = *reinterpret_cast<const float4*>(row + wb);
      c8[c][r][0] = a.x;  c8[c][r][1] = a.y;  c8[c][r][2] = a.z;  c8[c][r][3] = a.w;
      c8[c][r][4] = bb.x; c8[c][r][5] = bb.y; c8[c][r][6] = bb.z; c8[c][r][7] = bb.w;
    }
  }

  float* outp = out + (size_t)(b * OC) * (OH * OW) + (size_t)oh * OW + w0;
#pragma unroll 1
  for (int oc = 0; oc < OC; ++oc) {
    float fr[28];
#pragma unroll
    for (int q = 0; q < 7; ++q) {
      const float4 fv = *reinterpret_cast<const float4*>(&flds[oc * 28 + q * 4]);
      fr[q * 4 + 0] = fv.x; fr[q * 4 + 1] = fv.y;
      fr[q * 4 + 2] = fv.z; fr[q * 4 + 3] = fv.w;
    }
    float a0 = 0.f, a1 = 0.f, a2 = 0.f, a3 = 0.f;
#pragma unroll
    for (int c = 0; c < C; ++c)
#pragma unroll
      for (int r = 0; r < KS; ++r)
#pragma unroll
        for (int kw = 0; kw < KS; ++kw) {
          const float wv = fr[c * 9 + r * 3 + kw];
          a0 = fmaf(wv, c8[c][r][kw + 0], a0);
          a1 = fmaf(wv, c8[c][r][kw + 1], a1);
          a2 = fmaf(wv, c8[c][r][kw + 2], a2);
          a3 = fmaf(wv, c8[c][r][kw + 3], a3);
        }
    // Output row stride = 222 floats = 888 B -> only 8B-aligned: float2 stores.
    float* op = outp + (size_t)oc * (OH * OW);
    if (!tail) {
      *reinterpret_cast<float2*>(op + 0) = make_float2(a0, a1);
      *reinterpret_cast<float2*>(op + 2) = make_float2(a2, a3);
    } else {
      op[0] = a0;   // ow = 220
      op[1] = a1;   // ow = 221
    }
  }
}

extern "C" void kernel_launch(void* const* d_in, const int* in_sizes, int n_in,
                              void* d_out, int out_size, void* d_ws, size_t ws_size,
                              hipStream_t stream) {
  const float* x = (const float*)d_in[0];
  const float* f = (const float*)d_in[1];
  float* o       = (float*)d_out;
  const int grid = (TOTAL + BLOCK - 1) / BLOCK;
  conv3x3_kernel<<<grid, BLOCK, 0, stream>>>(x, f, o);
}

// Round 3
// 243.284 us; speedup vs baseline: 1.0674x; 1.0674x over previous
//
#include <hip/hip_runtime.h>

// Conv 3x3 VALID, NCHW/OIHW, fp32. x=[64,3,224,224], w=[16,3,3,3] -> out=[64,16,222,222].
// Memory-bound (202 MB output write, ~38 us floor). Each thread: 4 consecutive ow x all 16 oc.
// R3: filters via wave-uniform scalar loads (SGPR operand to v_fmac), no LDS, nt stores.

namespace {
constexpr int B  = 64, C = 3, H = 224, W = 224;
constexpr int OC = 16, KS = 3, OH = 222, OW = 222;
constexpr int NW4   = 56;               // ceil(OW/4)
constexpr int TOTAL = B * OH * NW4;     // 795,648 = 3108 * 256 exactly (no thread tail)
constexpr int BLOCK = 256;
typedef float f32x2 __attribute__((ext_vector_type(2)));
}

__global__ __launch_bounds__(BLOCK, 4) void conv3x3_kernel(
    const float* __restrict__ x, const float* __restrict__ flt,
    float* __restrict__ out) {
  const int tid = blockIdx.x * BLOCK + threadIdx.x;   // always < TOTAL (exact grid)
  const int g  = tid % NW4;
  const int t1 = tid / NW4;
  const int oh = t1 % OH;
  const int b  = t1 / OH;
  const int w0 = g * 4;
  const bool tail = (g == NW4 - 1);       // w0 == 220: only 2 valid outputs
  const int  wb   = tail ? w0 : w0 + 4;   // clamped second load (no OOB; duplicates cols)

  // 3x3 window over 8 input cols, 2 aligned float4 per (c,row) = 18 vec loads.
  float c8[C][KS][8];
  const float* xb = x + (size_t)b * (C * H * W);
#pragma unroll
  for (int c = 0; c < C; ++c) {
#pragma unroll
    for (int r = 0; r < KS; ++r) {
      const float* row = xb + (c * H + oh + r) * W;
      const float4 a  = *reinterpret_cast<const float4*>(row + w0);
      const float4 bb = *reinterpret_cast<const float4*>(row + wb);
      c8[c][r][0] = a.x;  c8[c][r][1] = a.y;  c8[c][r][2] = a.z;  c8[c][r][3] = a.w;
      c8[c][r][4] = bb.x; c8[c][r][5] = bb.y; c8[c][r][6] = bb.z; c8[c][r][7] = bb.w;
    }
  }

  float* outp = out + (size_t)(b * OC) * (OH * OW) + (size_t)oh * OW + w0;
#pragma unroll 1
  for (int oc = 0; oc < OC; ++oc) {
    // Wave-uniform index, uniform control flow -> compiler scalarizes to s_load;
    // filter values live in SGPRs and feed v_fmac_f32 as the scalar operand.
    float fv[27];
#pragma unroll
    for (int k = 0; k < 27; ++k) fv[k] = flt[oc * 27 + k];

    float a0 = 0.f, a1 = 0.f, a2 = 0.f, a3 = 0.f;
#pragma unroll
    for (int c = 0; c < C; ++c)
#pragma unroll
      for (int r = 0; r < KS; ++r)
#pragma unroll
        for (int kw = 0; kw < KS; ++kw) {
          const float wv = fv[c * 9 + r * 3 + kw];
          a0 = fmaf(wv, c8[c][r][kw + 0], a0);
          a1 = fmaf(wv, c8[c][r][kw + 1], a1);
          a2 = fmaf(wv, c8[c][r][kw + 2], a2);
          a3 = fmaf(wv, c8[c][r][kw + 3], a3);
        }

    // Output row stride = 888 B (8B-aligned only) -> float2 nontemporal stores.
    // nt: output is write-once/never-read; keep the 38.5 MB input L2-resident.
    float* op = outp + (size_t)oc * (OH * OW);
    if (!tail) {
      f32x2 v01; v01.x = a0; v01.y = a1;
      f32x2 v23; v23.x = a2; v23.y = a3;
      __builtin_nontemporal_store(v01, reinterpret_cast<f32x2*>(op));
      __builtin_nontemporal_store(v23, reinterpret_cast<f32x2*>(op) + 1);
    } else {
      __builtin_nontemporal_store(a0, op + 0);   // ow = 220
      __builtin_nontemporal_store(a1, op + 1);   // ow = 221
    }
  }
}

extern "C" void kernel_launch(void* const* d_in, const int* in_sizes, int n_in,
                              void* d_out, int out_size, void* d_ws, size_t ws_size,
                              hipStream_t stream) {
  const float* x = (const float*)d_in[0];
  const float* f = (const float*)d_in[1];
  float* o       = (float*)d_out;
  const int grid = TOTAL / BLOCK;   // exact
  conv3x3_kernel<<<grid, BLOCK, 0, stream>>>(x, f, o);
}